// Round 1
// baseline (289.971 us; speedup 1.0000x reference)
//
#include <hip/hip_runtime.h>
#include <hip/hip_bf16.h>

// K[i,j] = I0(2a*cos(pi*(x_i - y_j))) * exp(-2a),  a = 10
// Stable form: i0e(z) * exp(|z| - 2a), z = 2a*cos(pi*diff), |z| <= 2a.
//
// i0e via Abramowitz & Stegun 9.8.1 / 9.8.2 polynomial fits (|err| < 2e-7):
//   |z| <  3.75 :  I0(z) = poly(t^2), t = z/3.75        -> K = poly * exp(-2a)
//   |z| >= 3.75 :  sqrt(z)*i0e(z) = poly(3.75/z)        -> K = poly * rsqrt(z) * exp(z-2a)
//
// HW notes (gfx950): v_cos_f32 takes REVOLUTIONS -> cos(pi*d) = v_cos(0.5*d),
// d = x_i - y_j is in (-1,1) so no range reduction needed. exp(t) = exp2(t*log2e)
// via v_exp_f32. Both branches computed branchlessly (y is unsorted; adjacent
// lanes diverge randomly, so exec-mask branching would run both sides anyway).

#define TWO_A 20.0f
#define EXP_NEG_2A 2.0611536224385578e-9f   // exp(-20)
#define LOG2E 1.4426950408889634f

__device__ __forceinline__ float bessel_elem(float xi, float yj) {
    float d = xi - yj;                       // (-1, 1)
#if __has_builtin(__builtin_amdgcn_cosf)
    float c = __builtin_amdgcn_cosf(0.5f * d);   // cos(pi*d), revolutions input
#else
    float c = __cosf(3.14159265358979323846f * d);
#endif
    float az = TWO_A * fabsf(c);             // |z| in [0, 20]

    // small branch: I0(|z|), |z| < 3.75  (A&S 9.8.1)
    float t2 = az * (1.0f / 3.75f);
    t2 = t2 * t2;
    float ps = fmaf(t2, 0.0045813f, 0.0360768f);
    ps = fmaf(t2, ps, 0.2659732f);
    ps = fmaf(t2, ps, 1.2067492f);
    ps = fmaf(t2, ps, 3.0899424f);
    ps = fmaf(t2, ps, 3.5156229f);
    ps = fmaf(t2, ps, 1.0f);
    float k_small = ps * EXP_NEG_2A;

    // large branch: sqrt(|z|)*i0e(|z|), |z| >= 3.75  (A&S 9.8.2)
    float u = __fdividef(3.75f, az);         // fast rcp-based divide
    float pl = fmaf(u, 0.00392377f, -0.01647633f);
    pl = fmaf(u, pl, 0.02635537f);
    pl = fmaf(u, pl, -0.02057706f);
    pl = fmaf(u, pl, 0.00916281f);
    pl = fmaf(u, pl, -0.00157565f);
    pl = fmaf(u, pl, 0.00225319f);
    pl = fmaf(u, pl, 0.01328592f);
    pl = fmaf(u, pl, 0.39894228f);
    float e = exp2f((az - TWO_A) * LOG2E);   // exp(|z| - 2a) <= 1
    float k_large = pl * rsqrtf(az) * e;

    return (az < 3.75f) ? k_small : k_large;
}

__global__ __launch_bounds__(256) void bessel_kernel(
    const float* __restrict__ x, const float* __restrict__ y,
    float* __restrict__ out, int nx, int ny)
{
    const int i = blockIdx.y;
    const int j4 = (blockIdx.x * 256 + threadIdx.x) * 4;
    if (i >= nx || j4 >= ny) return;

    const float xi = x[i];                   // block-uniform -> scalar load
    float* orow = out + (size_t)i * (size_t)ny;

    if (j4 + 3 < ny) {
        float4 yv = *reinterpret_cast<const float4*>(y + j4);
        float4 o;
        o.x = bessel_elem(xi, yv.x);
        o.y = bessel_elem(xi, yv.y);
        o.z = bessel_elem(xi, yv.z);
        o.w = bessel_elem(xi, yv.w);
        *reinterpret_cast<float4*>(orow + j4) = o;
    } else {
        for (int j = j4; j < ny; ++j)
            orow[j] = bessel_elem(xi, y[j]);
    }
}

extern "C" void kernel_launch(void* const* d_in, const int* in_sizes, int n_in,
                              void* d_out, int out_size, void* d_ws, size_t ws_size,
                              hipStream_t stream) {
    const float* x = (const float*)d_in[0];
    const float* y = (const float*)d_in[1];
    float* out = (float*)d_out;
    const int nx = in_sizes[0];
    const int ny = in_sizes[1];

    const int jblocks = (ny + 4 * 256 - 1) / (4 * 256);   // 4 elems/thread
    dim3 grid(jblocks, nx);
    bessel_kernel<<<grid, 256, 0, stream>>>(x, y, out, nx, ny);
}